// Round 15
// baseline (114.697 us; speedup 1.0000x reference)
//
#include <hip/hip_runtime.h>

// Problem constants
#define SRC    16384     // 128*128 source pixels
#define DCH    64        // channels
#define NCLS   19        // classes
#define NPAIR  (NCLS*DCH)// 1216 (c,d) pairs

// GUARANTEED bare v_exp_f32 via inline asm (proven). CDNA VALU->VALU results
// are hardware-interlocked; no s_nop required.
__device__ __forceinline__ float exp2_raw(float x)
{
    float r;
    asm("v_exp_f32 %0, %1" : "=v"(r) : "v"(x));
    return r;
}

// ---------------------------------------------------------------------------
// K1: per-source-pixel class counts (proven). Also zeroes psum.
// ---------------------------------------------------------------------------
__global__ __launch_bounds__(256) void hl_count_kernel(
    const int* __restrict__ label, unsigned char* __restrict__ cnt,
    float* __restrict__ psum)
{
    if (blockIdx.x == 0 && threadIdx.x == 0) psum[0] = 0.f;
    int s  = blockIdx.x * 256 + threadIdx.x;   // 64 blocks x 256 = 16384
    int sy = s >> 7, sx = s & 127;
    const int4* lab4 = (const int4*)label;
    int l[16];
#pragma unroll
    for (int r = 0; r < 4; r++) {
        int4 v = lab4[(4 * sy + r) * 128 + sx];
        l[4 * r + 0] = v.x; l[4 * r + 1] = v.y;
        l[4 * r + 2] = v.z; l[4 * r + 3] = v.w;
    }
#pragma unroll
    for (int c = 0; c < NCLS; c++) {
        int cc = 0;
#pragma unroll
        for (int j = 0; j < 16; j++) cc += (l[j] == c) ? 1 : 0;
        cnt[c * SRC + s] = (unsigned char)cc;
    }
}

// ---------------------------------------------------------------------------
// K2: fused moments + KDE. One 256-thread block per (c,d), 64 px/thread.
// Pass 1: proven f64-reduced moments (unroll bumped 4->8 for deeper VMEM
//         pipelining -- R10 evidence suggests load latency is a co-bottleneck).
// Pass 2: 3-exp centered KDE with REGISTER cndmask scatter.
//   R10 ledger: 7-exp/register = 43.8us, 3-exp/LDS-RMW = 44.5us -> the LDS
//   scatter's alias-serialized ds_read->add->ds_write chain ate the 4-trans
//   saving. Fix: keep the (HW-verified, absmax 0.0) 3-exp value chain
//     E = exp2(C1 v^2); r = exp2(C2 v); ri = exp2(-C2 v)
//     t0 = cf*E; t1 = t0*(r*K1c); t2 = t1*(r*K2c);
//     tm1 = t0*(ri*K1c); tm2 = tm1*(ri*K2c)
//   and scatter via selects into 7 register accumulators: bin j takes
//     q==j -> t0 | q==j-1 -> t1 | q==j-2 -> t2 | q==j+1 -> tm1 | q==j+2 -> tm2
//   with q = k0+3 in [0,6] (impossible compares pruned): 7 v_cmp (shared) +
//   29 v_cndmask + 7 adds, all full-rate VALU, zero memory ops, no aliasing.
//   Dropped |o|>=3 terms are <= e^{-78} ~ 1.2e-34: invisible in f32 sums of
//   O(1e2..1e3) (adding 1e-34 to 100.0f is a no-op), so results are bit-equal.
//   Overflow guard: v clamped to +-3.4 keeps r <= 2^122.6 finite; the clamp
//   binds only where E flushes to 0 and every true bin underflows to 0 too.
// launch_bounds(256,4): proven no-spill budget.
// ---------------------------------------------------------------------------
__global__ __launch_bounds__(256, 4) void hl_fused_kernel(
    const float* __restrict__ feature, const unsigned char* __restrict__ cnt,
    int* __restrict__ ncls, float* __restrict__ psum)
{
    int w = blockIdx.x;             // pair 0..1215
    int c = w >> 6, d = w & 63;
    int t = threadIdx.x;
    int wid = t >> 6;

    const float4*       fp4 = (const float4*)(feature + d * SRC);
    const unsigned int* cpu = (const unsigned int*)(cnt + c * SRC);

    // ---- Pass 1: moments (proven; unroll 8 for more loads in flight) ------
    float f1 = 0.f, f2 = 0.f;
    int   nc = 0;
#pragma unroll 8
    for (int i = 0; i < 16; i++) {
        int g = i * 256 + t;        // 4096 float4-groups (= 4096 uint groups)
        float4       x  = fp4[g];
        unsigned int cv = cpu[g];
        float xs[4] = {x.x, x.y, x.z, x.w};
        float cf[4] = {(float)(cv & 255u), (float)((cv >> 8) & 255u),
                       (float)((cv >> 16) & 255u), (float)(cv >> 24)};
#pragma unroll
        for (int e = 0; e < 4; e++) {
            float wx = cf[e] * xs[e];
            f1 += wx;
            f2 = fmaf(wx, xs[e], f2);
        }
        nc += (cv & 255u) + ((cv >> 8) & 255u) + ((cv >> 16) & 255u) + (cv >> 24);
    }
    double s1 = (double)f1, s2 = (double)f2;
#pragma unroll
    for (int o = 32; o > 0; o >>= 1) {
        s1 += __shfl_down(s1, o);
        s2 += __shfl_down(s2, o);
        nc += __shfl_down(nc, o);
    }
    __shared__ double ps1[4], ps2[4];
    __shared__ int    pn[4];
    __shared__ float  sh_mu, sh_istd;
    __shared__ int    sh_act;
    if ((t & 63) == 0) { ps1[wid] = s1; ps2[wid] = s2; pn[wid] = nc; }
    __syncthreads();
    if (t == 0) {
        double a = ps1[0] + ps1[1] + ps1[2] + ps1[3];
        double b = ps2[0] + ps2[1] + ps2[2] + ps2[3];
        int    n = pn[0] + pn[1] + pn[2] + pn[3];
        double nsafe = (n > 0) ? (double)n : 1.0;
        double mu  = a / nsafe;
        double var = (b - 2.0 * mu * a + mu * mu * (double)n) / nsafe + 1e-10;
        sh_mu   = (float)mu;
        sh_istd = (float)(1.0 / sqrt(var));
        sh_act  = (n >= 1000);
        if (d == 0) ncls[c] = n;    // plain store; consumed only by K3
    }
    __syncthreads();
    if (!sh_act) return;            // inactive class: contributes 0
    float istd = sh_istd;
    float nm   = -sh_mu * istd;     // u = fma(x, istd, nm)

    // ---- Pass 2: KDE, 3-trans + register select scatter -------------------
    const float C1  = -18.033688011112042f;  // -12.5 * log2(e)
    const float C2  =  36.067376022224084f;  // +25   * log2(e)
    const float K1c =  3.72665317e-06f;      // e^{-12.5}
    const float K2c =  5.17555501e-17f;      // e^{-37.5}

    float acc[7] = {0.f, 0.f, 0.f, 0.f, 0.f, 0.f, 0.f};

#pragma unroll 2
    for (int i = 0; i < 16; i++) {
        int g = i * 256 + t;
        float4       x  = fp4[g];
        unsigned int cv = cpu[g];
        float xs[4] = {x.x, x.y, x.z, x.w};
        float cf[4] = {(float)(cv & 255u), (float)((cv >> 8) & 255u),
                       (float)((cv >> 16) & 255u), (float)(cv >> 24)};
#pragma unroll
        for (int e = 0; e < 4; e++) {
            float u   = fmaf(xs[e], istd, nm);
            float uc  = fminf(3.f, fmaxf(-3.f, u));
            float k0f = rintf(uc);                   // v_rndne, exact int
            float v   = u - k0f;
            v = fminf(3.4f, fmaxf(-3.4f, v));        // overflow guard only
            float c2v = C2 * v;
            float E   = exp2_raw((C1 * v) * v);      // e^{-12.5 v^2}
            float r   = exp2_raw(c2v);               // e^{+25 v}
            float ri  = exp2_raw(-c2v);              // e^{-25 v}
            float t0  = cf[e] * E;
            float t1  = t0  * (r  * K1c);            // e^{-12.5(v-1)^2}
            float t2  = t1  * (r  * K2c);            // e^{-12.5(v-2)^2}
            float tm1 = t0  * (ri * K1c);            // e^{-12.5(v+1)^2}
            float tm2 = tm1 * (ri * K2c);            // e^{-12.5(v+2)^2}
            int   q   = (int)k0f + 3;                // center bin index, 0..6
            // register scatter: bin j = q+o gets the o-offset value
#pragma unroll
            for (int j = 0; j < 7; j++) {
                float wv = 0.f;
                if (j >= 2) wv = (q == j - 2) ? t2  : wv;
                if (j >= 1) wv = (q == j - 1) ? t1  : wv;
                wv = (q == j) ? t0 : wv;
                if (j <= 5) wv = (q == j + 1) ? tm1 : wv;
                if (j <= 4) wv = (q == j + 2) ? tm2 : wv;
                acc[j] += wv;
            }
        }
    }

    __shared__ float part[4][7];
#pragma unroll
    for (int j = 0; j < 7; j++) {
        float v = acc[j];
#pragma unroll
        for (int o = 32; o > 0; o >>= 1) v += __shfl_down(v, o);
        if ((t & 63) == 0) part[wid][j] = v;
    }
    __syncthreads();

    if (t == 0) {
        // target: exp(-0.5 k^2)/Z (1/sqrt(2 pi var) cancels in normalization)
        double e[7], z = 0.0;
#pragma unroll
        for (int k = -3; k <= 3; k++) { e[k + 3] = exp(-0.5 * (double)(k * k)); z += e[k + 3]; }

        float hist7[7], S = 0.f;
#pragma unroll
        for (int j = 0; j < 7; j++) {
            hist7[j] = part[0][j] + part[1][j] + part[2][j] + part[3][j];
            S += hist7[j];
        }
        float Ss = fmaxf(S, 1e-30f);
        float ps = 0.f;
#pragma unroll
        for (int j = 0; j < 7; j++) {
            float dd = fabsf(hist7[j] / Ss - (float)(e[j] / z));
            ps += (dd < 1.f) ? 0.5f * dd * dd : (dd - 0.5f);
        }
        atomicAdd(psum, ps);        // raw partial; scaled once in K3
    }
}

// ---------------------------------------------------------------------------
// K3: finalize. A = #active classes; out = psum / (448 * A). Writes out
// absolutely (harness-poisoned d_out needs no pre-zero).
// ---------------------------------------------------------------------------
__global__ __launch_bounds__(64) void hl_final_kernel(
    const float* __restrict__ psum, const int* __restrict__ ncls,
    float* __restrict__ out)
{
    if (threadIdx.x == 0) {
        int A = 0;
#pragma unroll
        for (int i = 0; i < NCLS; i++) A += (ncls[i] >= 1000) ? 1 : 0;
        out[0] = (A > 0) ? psum[0] / (448.0f * (float)A) : 0.0f;
    }
}

// ---------------------------------------------------------------------------
extern "C" void kernel_launch(void* const* d_in, const int* in_sizes, int n_in,
                              void* d_out, int out_size, void* d_ws, size_t ws_size,
                              hipStream_t stream)
{
    const float* feature = (const float*)d_in[0];   // [1,64,128,128] fp32
    const int*   label   = (const int*)d_in[1];     // [1,1,512,512]  int32
    float*       out     = (float*)d_out;           // scalar fp32

    char* ws = (char*)d_ws;
    unsigned char* cnt  = (unsigned char*)(ws);      // 311296 B
    int*           ncls = (int*)(ws + 311296);       // 76 B
    float*         psum = (float*)(ws + 311424);     // 4 B

    hl_count_kernel<<<SRC / 256, 256, 0, stream>>>(label, cnt, psum);
    hl_fused_kernel<<<NPAIR, 256, 0, stream>>>(feature, cnt, ncls, psum);
    hl_final_kernel<<<1, 64, 0, stream>>>(psum, ncls, out);
}